// Round 10
// baseline (355.416 us; speedup 1.0000x reference)
//
#include <hip/hip_runtime.h>
#include <hip/hip_bf16.h>
#include <hip/hip_fp16.h>

// Problem constants
#define NB 16
#define DD 64
#define HW 4096          // 64*64
#define NTOT 65536       // NB*HW
#define KC 1024

// Output chunk offsets (FLOAT32 elements, return order)
#define O_EK   0
#define O_IDX  4194304
#define O_L    4259840
#define O_CB   4259841
#define O_CNT  4325377
#define O_SUM  4326401

// Workspace layout (float element offsets)
#define WS_IDX    0          // [0, 32768) as ushort[65536]
#define WS_LCPART 65536      // 256 floats used
#define WS_N      66048      // scalar
#define WS_DONE   66304      // int: k_out completion counter
#define WS_CNORM  66560      // 1024
#define WS_PSUM   67584      // 4 x 65536 -> ends 329728
#define WS_PCNT   329728     // 4 x 1024 ints -> ends 333824
#define WS_CBH    399360     // 65536 ushort (-2x scaled, hi)
#define WS_CBL    432128     // 65536 ushort (-2x scaled, lo)

typedef _Float16 v8h __attribute__((ext_vector_type(8)));
typedef float    v4f __attribute__((ext_vector_type(4)));
typedef unsigned short ush;

// cnorm + n + codebook (-2x scaled) fp16 hi/lo split + done-counter reset
__global__ __launch_bounds__(256) void k_pre(const float* __restrict__ cb,
                                             const float* __restrict__ ema_count,
                                             float* __restrict__ cnorm,
                                             float* __restrict__ n_ws,
                                             unsigned short* __restrict__ cbh,
                                             unsigned short* __restrict__ cbl,
                                             int* __restrict__ done_ctr) {
    const int t = threadIdx.x;
    const int w = (blockIdx.x * 256 + t) >> 6;   // code 0..1023 (grid 256)
    const int l = t & 63;
    float s = 0.f;
    if (l < 16) {
        float4 v = *(const float4*)(cb + (size_t)w * DD + l * 4);
        s = v.x * v.x + v.y * v.y + v.z * v.z + v.w * v.w;
    }
#pragma unroll
    for (int m = 1; m <= 8; m <<= 1) s += __shfl_xor(s, m, 64);
    if (l == 0) cnorm[w] = s;

    // fp16 hi/lo conversion with -2x fold: 16384 float4s, row-major layout
    const int e4 = blockIdx.x * 256 + t;
    if (e4 < 16384) {
        float4 v4 = ((const float4*)cb)[e4];
        float sx = -2.f * v4.x, sy = -2.f * v4.y, sz = -2.f * v4.z, sw = -2.f * v4.w;
        __half hx = __float2half(sx), hy = __float2half(sy),
               hz = __float2half(sz), hw2 = __float2half(sw);
        ushort4 h4 = { __half_as_ushort(hx), __half_as_ushort(hy),
                       __half_as_ushort(hz), __half_as_ushort(hw2) };
        ((ushort4*)cbh)[e4] = h4;
        ushort4 l4 = { __half_as_ushort(__float2half(sx - __half2float(hx))),
                       __half_as_ushort(__float2half(sy - __half2float(hy))),
                       __half_as_ushort(__float2half(sz - __half2float(hz))),
                       __half_as_ushort(__float2half(sw - __half2float(hw2))) };
        ((ushort4*)cbl)[e4] = l4;
    }

    if (blockIdx.x == 0) {
        if (t == 0) done_ctr[0] = 0;   // kernel boundary makes this device-visible
        __shared__ float red[256];
        red[t] = ema_count[t] + ema_count[t + 256] + ema_count[t + 512] + ema_count[t + 768];
        __syncthreads();
        for (int s2 = 128; s2 >= 1; s2 >>= 1) {
            if (t < s2) red[t] += red[t + s2];
            __syncthreads();
        }
        if (t == 0) n_ws[0] = 0.99f * red[0] + 0.01f * 65536.0f;
    }
}

// MFMA argmin (R8 config, session best — byte-identical). 512 threads = 8
// waves, 16 rows/wave. __launch_bounds__(512,3) caps VGPR at ~85 so three
// blocks fit per CU (24 waves/CU). Distance = raw MFMA accumulator (-2
// folded into cbh/cbl, cnorm preloaded into C). Top-2 via fmed3+min on
// index-packed floats; exact fp32 recheck for near-ties.
__global__ __launch_bounds__(512, 3) void k_argmin(const float* __restrict__ z_e,
                                                   const float* __restrict__ cbf,
                                                   const unsigned short* __restrict__ cbh,
                                                   const unsigned short* __restrict__ cbl,
                                                   const float* __restrict__ cnorm,
                                                   unsigned short* __restrict__ idx16,
                                                   float* __restrict__ out) {
    __shared__ __align__(16) unsigned char ldsAB[32768];   // A2h|A2l staging, then B2h|B2l
    __shared__ __align__(16) float slab[2048];             // 8 KB: 16 j-rows x 128 m
    __shared__ int idx_lds[128];
    __shared__ int flagrows[128];
    __shared__ int flagi1[128];
    __shared__ int flagi2[128];
    __shared__ int nflag;

    ush (*A2h)[128][8]  = (ush(*)[128][8])(ldsAB);          // [8][128][8] (staging phase)
    ush (*A2l)[128][8]  = (ush(*)[128][8])(ldsAB + 16384);
    ush (*B2h)[8][64][8] = (ush(*)[8][64][8])(ldsAB);       // [2][8][64][8] (loop phase)
    ush (*B2l)[8][64][8] = (ush(*)[8][64][8])(ldsAB + 16384);

    const int t  = threadIdx.x;
    const int n0 = blockIdx.x * 128;
    const int bb  = n0 >> 12;
    const int hw0 = n0 & 4095;
    const float* zbase = z_e + (size_t)bb * (DD * HW) + hw0;

    if (t == 0) nflag = 0;

    // ---- A staging: 4 passes of 16 j-rows; coalesced fp32 load, hi/lo convert ----
    {
        const int jr   = t >> 5;            // 0..15
        const int m4   = (t & 31) << 2;
        const int chl  = t >> 8;            // 0..1 local chunk
        const int cm   = t & 127;
        const int half = (t >> 7) & 1;
        for (int sl = 0; sl < 4; ++sl) {
            if (sl) __syncthreads();        // slab readers of previous pass done
            float4 v = *(const float4*)(zbase + (size_t)(sl * 16 + jr) * HW + m4);
            *(float4*)&slab[jr * 128 + m4] = v;
            __syncthreads();
            unsigned hv[2], lv[2];
#pragma unroll
            for (int p = 0; p < 2; ++p) {
                int jj = chl * 8 + half * 4 + p * 2;
                float v0 = slab[jj * 128 + cm];
                float v1 = slab[(jj + 1) * 128 + cm];
                __half h0 = __float2half(v0), h1 = __float2half(v1);
                __half l0 = __float2half(v0 - __half2float(h0));
                __half l1 = __float2half(v1 - __half2float(h1));
                hv[p] = (unsigned)__half_as_ushort(h0) | ((unsigned)__half_as_ushort(h1) << 16);
                lv[p] = (unsigned)__half_as_ushort(l0) | ((unsigned)__half_as_ushort(l1) << 16);
            }
            uint2 hq = {hv[0], hv[1]}, lq = {lv[0], lv[1]};
            *(uint2*)&A2h[sl * 2 + chl][cm][half * 4] = hq;
            *(uint2*)&A2l[sl * 2 + chl][cm][half * 4] = lq;
        }
    }
    __syncthreads();                        // A2 complete

    const int w    = t >> 6;        // wave 0..7 -> rows [16w, 16w+16)
    const int lane = t & 63;
    const int c    = lane & 15;     // col within 16-tile
    const int q    = lane >> 4;     // k-quad / row-quad

    // A fragments, loaded once: [K-step s]; chunk = s*4 + q
    v8h Afh[2], Afl[2];
    {
        int m = 16 * w + c;
#pragma unroll
        for (int s = 0; s < 2; ++s) {
            Afh[s] = *(const v8h*)&A2h[s * 4 + q][m][0];
            Afl[s] = *(const v8h*)&A2l[s * 4 + q][m][0];
        }
    }
    __syncthreads();                // all A2 reads done; ldsAB becomes B buffers

    // staging decomposition: 512 threads, 1 uint4 each from cbh/cbl
    const int ch0   = t >> 6;       // 0..7
    const int code0 = t & 63;

    // ---- prologue: stage B tile 0 into buffer 0 ----
    {
        size_t g0 = ((size_t)code0) * 64 + ch0 * 8;
        *(uint4*)&B2h[0][ch0][code0][0] = *(const uint4*)(cbh + g0);
        *(uint4*)&B2l[0][ch0][code0][0] = *(const uint4*)(cbl + g0);
    }
    __syncthreads();

    float m1f[4], m2f[4];
#pragma unroll
    for (int r = 0; r < 4; ++r) { m1f[r] = 3.4e38f; m2f[r] = 3.4e38f; }

    for (int kt = 0; kt < 16; ++kt) {
        const int cur = kt & 1, nxt = cur ^ 1;
        // prefetch tile kt+1 into VGPRs (loads overlap compute below)
        uint4 ph0, pl0;
        if (kt < 15) {
            size_t g0 = ((size_t)((kt + 1) * 64 + code0)) * 64 + ch0 * 8;
            ph0 = *(const uint4*)(cbh + g0);
            pl0 = *(const uint4*)(cbl + g0);
        }

        // compute tile kt from buf[cur]: 4 independent 6-MFMA chains
#pragma unroll
        for (int sub = 0; sub < 4; ++sub) {
            const int cl = sub * 16 + c;
            v8h Bfh0 = *(const v8h*)&B2h[cur][q][cl][0];
            v8h Bfh1 = *(const v8h*)&B2h[cur][4 + q][cl][0];
            v8h Bfl0 = *(const v8h*)&B2l[cur][q][cl][0];
            v8h Bfl1 = *(const v8h*)&B2l[cur][4 + q][cl][0];
            const unsigned kg = (unsigned)(kt * 64 + cl);
            const float cnc = cnorm[kg];    // 4 KB array, L1-hot
            v4f acc = {cnc, cnc, cnc, cnc}; // ||c||^2 preloaded; -2 folded in B
            acc = __builtin_amdgcn_mfma_f32_16x16x32_f16(Afh[0], Bfh0, acc, 0, 0, 0);
            acc = __builtin_amdgcn_mfma_f32_16x16x32_f16(Afh[1], Bfh1, acc, 0, 0, 0);
            acc = __builtin_amdgcn_mfma_f32_16x16x32_f16(Afh[0], Bfl0, acc, 0, 0, 0);
            acc = __builtin_amdgcn_mfma_f32_16x16x32_f16(Afh[1], Bfl1, acc, 0, 0, 0);
            acc = __builtin_amdgcn_mfma_f32_16x16x32_f16(Afl[0], Bfh0, acc, 0, 0, 0);
            acc = __builtin_amdgcn_mfma_f32_16x16x32_f16(Afl[1], Bfh1, acc, 0, 0, 0);
#pragma unroll
            for (int r = 0; r < 4; ++r) {
                // pack code index into low 10 mantissa bits (v_and_or_b32)
                unsigned vu = (__float_as_uint(acc[r]) & 0xFFFFFC00u) | kg;
                float vp = __uint_as_float(vu);
                // top-2 update: 2 ops (med3 + min)
                m2f[r] = __builtin_amdgcn_fmed3f(m1f[r], m2f[r], vp);
                m1f[r] = fminf(m1f[r], vp);
            }
        }

        // write prefetched tile into buf[nxt] (its readers passed the last barrier)
        if (kt < 15) {
            *(uint4*)&B2h[nxt][ch0][code0][0] = ph0;
            *(uint4*)&B2l[nxt][ch0][code0][0] = pl0;
        }
        __syncthreads();                    // single barrier per iteration
    }

    // ---- top-2 merge across the 16 lanes holding each row ----
#pragma unroll
    for (int r = 0; r < 4; ++r) {
        float a = m1f[r], b2 = m2f[r];
#pragma unroll
        for (int mask = 1; mask <= 8; mask <<= 1) {
            float o1 = __shfl_xor(a, mask, 64);
            float o2 = __shfl_xor(b2, mask, 64);
            float mx = fmaxf(a, o1);        // loser of champion duel
            a  = fminf(a, o1);
            b2 = fminf(fminf(b2, o2), mx);  // v_min3
        }
        if (c == 0) {
            int row = 16 * w + q * 4 + r;
            int i1 = (int)(__float_as_uint(a) & 1023u);
            idx_lds[row] = i1;
            // margin covers index-packing noise (<= |v|*4.9e-4) + fp16 hi/lo error
            float margin = fmaf(fabsf(a), 6e-4f, 0.0015f);
            if (b2 - a < margin) {
                int p = atomicAdd(&nflag, 1);
                flagrows[p] = row;
                flagi1[p] = i1;
                flagi2[p] = (int)(__float_as_uint(b2) & 1023u);
            }
        }
    }
    __syncthreads();

    // ---- exact fp32 top-2 recheck for flagged rows (one wave per row) ----
    {
        int nf = nflag;
        for (int f = w; f < nf; f += 8) {
            int row = flagrows[f], i1 = flagi1[f], i2x = flagi2[f];
            const float* zrow = zbase + row;
            float zj = zrow[(size_t)lane * HW];
            float p1 = zj * cbf[(size_t)i1  * DD + lane];
            float p2 = zj * cbf[(size_t)i2x * DD + lane];
#pragma unroll
            for (int mask = 1; mask <= 32; mask <<= 1) {
                p1 += __shfl_xor(p1, mask, 64);
                p2 += __shfl_xor(p2, mask, 64);
            }
            if (lane == 0) {
                float d1 = fmaf(-2.0f, p1, cnorm[i1]);
                float d2 = fmaf(-2.0f, p2, cnorm[i2x]);
                if (d2 < d1 || (d2 == d1 && i2x < i1)) idx_lds[row] = i2x;
            }
        }
    }
    __syncthreads();

    if (t < 128) {
        int bi = idx_lds[t];
        out[O_IDX + n0 + t] = (float)bi;
        idx16[n0 + t] = (unsigned short)bi;
    }
}

// Fused output pass + epilogue: 256 blocks (j, chunk c). Reads z once:
// e_k_ste + segment sums + histogram (j==0) + L_commit partials. The LAST
// block to finish (device-scope counter, rocPRIM-style) runs the old k_epi
// body — saves one kernel launch + its gap.
__global__ __launch_bounds__(1024) void k_out(const unsigned short* __restrict__ idx16,
                                              const float* __restrict__ z_e,
                                              const float* __restrict__ cb,
                                              float* __restrict__ psum,
                                              int* __restrict__ pcnt,
                                              float* __restrict__ lc_part,
                                              const float* __restrict__ ema_sum,
                                              const float* __restrict__ ema_count,
                                              const float* __restrict__ n_ws,
                                              int* __restrict__ done_ctr,
                                              float* __restrict__ out) {
    __shared__ float acc[KC];
    __shared__ int bins[KC];
    __shared__ float cbj[KC];
    __shared__ float lcr[16];
    __shared__ float red[256];
    __shared__ int amLast;
    const int j = blockIdx.x & 63;
    const int c = blockIdx.x >> 6;
    const int t = threadIdx.x;
    acc[t] = 0.f;
    bins[t] = 0;
    cbj[t] = cb[(size_t)t * DD + j];   // codebook column j (once per block)
    __syncthreads();
    const float* zj = z_e + (size_t)j * HW;
    float* oj = out + O_EK + (size_t)j * HW;
    const int base = c * 16384;
    float lc = 0.f;
#pragma unroll
    for (int i = 0; i < 4; ++i) {
        int n4 = base + i * 4096 + t * 4;
        int b = n4 >> 12, hw = n4 & 4095;
        size_t zoff = (size_t)b * (DD * HW) + hw;
        float4 z4 = *(const float4*)(zj + zoff);
        ushort4 k4 = *(const ushort4*)(idx16 + n4);
        float e0 = cbj[k4.x], e1 = cbj[k4.y], e2 = cbj[k4.z], e3 = cbj[k4.w];
        float4 o4 = { z4.x + (e0 - z4.x), z4.y + (e1 - z4.y),
                      z4.z + (e2 - z4.z), z4.w + (e3 - z4.w) };
        *(float4*)(oj + zoff) = o4;                       // coalesced
        float d0 = z4.x - e0, d1 = z4.y - e1, d2 = z4.z - e2, d3 = z4.w - e3;
        lc = fmaf(d0, d0, lc); lc = fmaf(d1, d1, lc);
        lc = fmaf(d2, d2, lc); lc = fmaf(d3, d3, lc);
        atomicAdd(&acc[k4.x], z4.x);
        atomicAdd(&acc[k4.y], z4.y);
        atomicAdd(&acc[k4.z], z4.z);
        atomicAdd(&acc[k4.w], z4.w);
        if (j == 0) {
            atomicAdd(&bins[k4.x], 1); atomicAdd(&bins[k4.y], 1);
            atomicAdd(&bins[k4.z], 1); atomicAdd(&bins[k4.w], 1);
        }
    }
    __syncthreads();
    psum[(size_t)c * 65536 + j * 1024 + t] = acc[t];
    if (j == 0) pcnt[c * 1024 + t] = bins[t];
#pragma unroll
    for (int m = 32; m >= 1; m >>= 1) lc += __shfl_xor(lc, m, 64);
    if ((t & 63) == 0) lcr[t >> 6] = lc;
    __syncthreads();
    if (t == 0) {
        float s = 0.f;
#pragma unroll
        for (int u = 0; u < 16; ++u) s += lcr[u];
        lc_part[blockIdx.x] = s;
    }

    // ---- last-block-done epilogue (was k_epi) ----
    __threadfence();                        // release: psum/pcnt/lc_part visible
    if (t == 0) amLast = (atomicAdd(done_ctr, 1) == 255);
    __syncthreads();
    if (!amLast) return;
    __threadfence();                        // acquire: see all blocks' partials

    const float n = n_ws[0];
    for (int it = 0; it < 64; ++it) {
        const int e = it * 1024 + t;
        const int k = e >> 6, jj = e & 63;
        float s4 = psum[jj * 1024 + k] + psum[65536 + jj * 1024 + k]
                 + psum[131072 + jj * 1024 + k] + psum[196608 + jj * 1024 + k];
        float ns = ema_sum[e] * 0.99f + 0.01f * s4;
        out[O_SUM + e] = ns;
        int cnt = pcnt[k] + pcnt[1024 + k] + pcnt[2048 + k] + pcnt[3072 + k];
        float nc = ema_count[k] * 0.99f + 0.01f * (float)cnt;
        float cs = (nc + 1e-5f) / (n + 1024.0f * 1e-5f) * n;
        out[O_CB + e] = ns / cs;
    }
    {
        int c2 = pcnt[t] + pcnt[1024 + t] + pcnt[2048 + t] + pcnt[3072 + t];
        out[O_CNT + t] = ema_count[t] * 0.99f + 0.01f * (float)c2;
    }
    if (t < 256) red[t] = lc_part[t];
    __syncthreads();
    for (int s = 128; s >= 1; s >>= 1) {
        if (t < s) red[t] += red[t + s];
        __syncthreads();
    }
    if (t == 0) out[O_L] = 1.25f * red[0] * (1.0f / 4194304.0f);
}

extern "C" void kernel_launch(void* const* d_in, const int* in_sizes, int n_in,
                              void* d_out, int out_size, void* d_ws, size_t ws_size,
                              hipStream_t stream) {
    const float* z_e       = (const float*)d_in[0];
    const float* cb        = (const float*)d_in[1];
    const float* ema_count = (const float*)d_in[2];
    const float* ema_sum   = (const float*)d_in[3];
    float* out             = (float*)d_out;

    float* ws_f      = (float*)d_ws;
    unsigned short* idx16 = (unsigned short*)d_ws;
    float* lc_part   = ws_f + WS_LCPART;
    float* n_ws      = ws_f + WS_N;
    int*   done_ctr  = (int*)(ws_f + WS_DONE);
    float* cnorm_ws  = ws_f + WS_CNORM;
    float* psum      = ws_f + WS_PSUM;
    int*   pcnt      = (int*)(ws_f + WS_PCNT);
    unsigned short* cbh = (unsigned short*)(ws_f + WS_CBH);
    unsigned short* cbl = (unsigned short*)(ws_f + WS_CBL);

    k_pre<<<256, 256, 0, stream>>>(cb, ema_count, cnorm_ws, n_ws, cbh, cbl, done_ctr);
    k_argmin<<<NTOT / 128, 512, 0, stream>>>(z_e, cb, cbh, cbl, cnorm_ws, idx16, out);
    k_out<<<256, 1024, 0, stream>>>(idx16, z_e, cb, psum, pcnt, lc_part,
                                    ema_sum, ema_count, n_ws, done_ctr, out);
}

// Round 11
// 137.459 us; speedup vs baseline: 2.5856x; 2.5856x over previous
//
#include <hip/hip_runtime.h>
#include <hip/hip_bf16.h>
#include <hip/hip_fp16.h>

// Problem constants
#define NB 16
#define DD 64
#define HW 4096          // 64*64
#define NTOT 65536       // NB*HW
#define KC 1024

// Output chunk offsets (FLOAT32 elements, return order)
#define O_EK   0
#define O_IDX  4194304
#define O_L    4259840
#define O_CB   4259841
#define O_CNT  4325377
#define O_SUM  4326401

// Workspace layout (float element offsets)
#define WS_IDX    0          // [0, 32768) as ushort[65536]
#define WS_LCPART 65536      // 256 floats used
#define WS_N      66048      // scalar
#define WS_CNORM  66560      // 1024
#define WS_PSUM   67584      // 4 x 65536 -> ends 329728
#define WS_PCNT   329728     // 4 x 1024 ints -> ends 333824
#define WS_CBH    399360     // 65536 ushort (-2x scaled, hi)
#define WS_CBL    432128     // 65536 ushort (-2x scaled, lo)

typedef _Float16 v8h __attribute__((ext_vector_type(8)));
typedef float    v4f __attribute__((ext_vector_type(4)));
typedef unsigned short ush;

// async global->LDS, 16B per lane (dest must be wave-uniform base + lane*16)
__device__ __forceinline__ void gload16(const void* g, void* l) {
    __builtin_amdgcn_global_load_lds(
        (const __attribute__((address_space(1))) unsigned int*)g,
        (__attribute__((address_space(3))) unsigned int*)l, 16, 0, 0);
}

// cnorm + n + codebook (-2x scaled) fp16 hi/lo split, row-major
__global__ __launch_bounds__(256) void k_pre(const float* __restrict__ cb,
                                             const float* __restrict__ ema_count,
                                             float* __restrict__ cnorm,
                                             float* __restrict__ n_ws,
                                             unsigned short* __restrict__ cbh,
                                             unsigned short* __restrict__ cbl) {
    const int t = threadIdx.x;
    const int w = (blockIdx.x * 256 + t) >> 6;   // code 0..1023 (grid 256)
    const int l = t & 63;
    float s = 0.f;
    if (l < 16) {
        float4 v = *(const float4*)(cb + (size_t)w * DD + l * 4);
        s = v.x * v.x + v.y * v.y + v.z * v.z + v.w * v.w;
    }
#pragma unroll
    for (int m = 1; m <= 8; m <<= 1) s += __shfl_xor(s, m, 64);
    if (l == 0) cnorm[w] = s;

    // fp16 hi/lo conversion with -2x fold: 16384 float4s, row-major layout
    const int e4 = blockIdx.x * 256 + t;
    if (e4 < 16384) {
        float4 v4 = ((const float4*)cb)[e4];
        float sx = -2.f * v4.x, sy = -2.f * v4.y, sz = -2.f * v4.z, sw = -2.f * v4.w;
        __half hx = __float2half(sx), hy = __float2half(sy),
               hz = __float2half(sz), hw2 = __float2half(sw);
        ushort4 h4 = { __half_as_ushort(hx), __half_as_ushort(hy),
                       __half_as_ushort(hz), __half_as_ushort(hw2) };
        ((ushort4*)cbh)[e4] = h4;
        ushort4 l4 = { __half_as_ushort(__float2half(sx - __half2float(hx))),
                       __half_as_ushort(__float2half(sy - __half2float(hy))),
                       __half_as_ushort(__float2half(sz - __half2float(hz))),
                       __half_as_ushort(__float2half(sw - __half2float(hw2))) };
        ((ushort4*)cbl)[e4] = l4;
    }

    if (blockIdx.x == 0) {
        __shared__ float red[256];
        red[t] = ema_count[t] + ema_count[t + 256] + ema_count[t + 512] + ema_count[t + 768];
        __syncthreads();
        for (int s2 = 128; s2 >= 1; s2 >>= 1) {
            if (t < s2) red[t] += red[t + s2];
            __syncthreads();
        }
        if (t == 0) n_ws[0] = 0.99f * red[0] + 0.01f * 65536.0f;
    }
}

// MFMA argmin (R8 config, session best) + async B staging via global_load_lds:
// the B tile DMAs directly into LDS while MFMAs run (no VGPR round-trip, no
// ds_write). Dest satisfies the wave-uniform-base + lane*16 constraint:
// wave w stages B2h[nxt][w][lane] (contiguous 1KB), per-lane global src.
// 512 threads = 8 waves, 16 rows/wave; __launch_bounds__(512,3) keeps three
// blocks per CU. Distance = raw MFMA accumulator (-2 folded into cbh/cbl,
// cnorm preloaded into C). Top-2 via fmed3+min on index-packed floats.
__global__ __launch_bounds__(512, 3) void k_argmin(const float* __restrict__ z_e,
                                                   const float* __restrict__ cbf,
                                                   const unsigned short* __restrict__ cbh,
                                                   const unsigned short* __restrict__ cbl,
                                                   const float* __restrict__ cnorm,
                                                   unsigned short* __restrict__ idx16,
                                                   float* __restrict__ out) {
    __shared__ __align__(16) unsigned char ldsAB[32768];   // A2h|A2l staging, then B2h|B2l
    __shared__ __align__(16) float slab[2048];             // 8 KB: 16 j-rows x 128 m
    __shared__ int idx_lds[128];
    __shared__ int flagrows[128];
    __shared__ int flagi1[128];
    __shared__ int flagi2[128];
    __shared__ int nflag;

    ush (*A2h)[128][8]  = (ush(*)[128][8])(ldsAB);          // [8][128][8] (staging phase)
    ush (*A2l)[128][8]  = (ush(*)[128][8])(ldsAB + 16384);
    ush (*B2h)[8][64][8] = (ush(*)[8][64][8])(ldsAB);       // [2][8][64][8] (loop phase)
    ush (*B2l)[8][64][8] = (ush(*)[8][64][8])(ldsAB + 16384);

    const int t  = threadIdx.x;
    const int n0 = blockIdx.x * 128;
    const int bb  = n0 >> 12;
    const int hw0 = n0 & 4095;
    const float* zbase = z_e + (size_t)bb * (DD * HW) + hw0;

    if (t == 0) nflag = 0;

    // ---- A staging: 4 passes of 16 j-rows; coalesced fp32 load, hi/lo convert ----
    {
        const int jr   = t >> 5;            // 0..15
        const int m4   = (t & 31) << 2;
        const int chl  = t >> 8;            // 0..1 local chunk
        const int cm   = t & 127;
        const int half = (t >> 7) & 1;
        for (int sl = 0; sl < 4; ++sl) {
            if (sl) __syncthreads();        // slab readers of previous pass done
            float4 v = *(const float4*)(zbase + (size_t)(sl * 16 + jr) * HW + m4);
            *(float4*)&slab[jr * 128 + m4] = v;
            __syncthreads();
            unsigned hv[2], lv[2];
#pragma unroll
            for (int p = 0; p < 2; ++p) {
                int jj = chl * 8 + half * 4 + p * 2;
                float v0 = slab[jj * 128 + cm];
                float v1 = slab[(jj + 1) * 128 + cm];
                __half h0 = __float2half(v0), h1 = __float2half(v1);
                __half l0 = __float2half(v0 - __half2float(h0));
                __half l1 = __float2half(v1 - __half2float(h1));
                hv[p] = (unsigned)__half_as_ushort(h0) | ((unsigned)__half_as_ushort(h1) << 16);
                lv[p] = (unsigned)__half_as_ushort(l0) | ((unsigned)__half_as_ushort(l1) << 16);
            }
            uint2 hq = {hv[0], hv[1]}, lq = {lv[0], lv[1]};
            *(uint2*)&A2h[sl * 2 + chl][cm][half * 4] = hq;
            *(uint2*)&A2l[sl * 2 + chl][cm][half * 4] = lq;
        }
    }
    __syncthreads();                        // A2 complete

    const int w    = t >> 6;        // wave 0..7 -> rows [16w, 16w+16)
    const int lane = t & 63;
    const int c    = lane & 15;     // col within 16-tile
    const int q    = lane >> 4;     // k-quad / row-quad

    // A fragments, loaded once: [K-step s]; chunk = s*4 + q
    v8h Afh[2], Afl[2];
    {
        int m = 16 * w + c;
#pragma unroll
        for (int s = 0; s < 2; ++s) {
            Afh[s] = *(const v8h*)&A2h[s * 4 + q][m][0];
            Afl[s] = *(const v8h*)&A2l[s * 4 + q][m][0];
        }
    }
    __syncthreads();                // all A2 reads done; ldsAB becomes B buffers

    // staging decomposition: wave w stages chunk w, lane = code (0..63)
    // dest = &B2h[buf][w][0][0] + lane*16 -> wave-uniform base + lane*16
    const int ch0   = t >> 6;       // == w
    const int code0 = t & 63;       // == lane

    // ---- prologue: stage B tile 0 into buffer 0 (async DMA) ----
    {
        size_t g0 = ((size_t)code0) * 64 + ch0 * 8;
        gload16(cbh + g0, &B2h[0][ch0][code0][0]);
        gload16(cbl + g0, &B2l[0][ch0][code0][0]);
    }
    __syncthreads();                // drains vmcnt -> tile 0 resident

    float m1f[4], m2f[4];
#pragma unroll
    for (int r = 0; r < 4; ++r) { m1f[r] = 3.4e38f; m2f[r] = 3.4e38f; }

    for (int kt = 0; kt < 16; ++kt) {
        const int cur = kt & 1, nxt = cur ^ 1;
        // async-stage tile kt+1 into buf[nxt]; lands under the MFMAs below,
        // handed off by the barrier's implicit vmcnt drain
        if (kt < 15) {
            size_t g0 = ((size_t)((kt + 1) * 64 + code0)) * 64 + ch0 * 8;
            gload16(cbh + g0, &B2h[nxt][ch0][code0][0]);
            gload16(cbl + g0, &B2l[nxt][ch0][code0][0]);
        }

        // compute tile kt from buf[cur]: 4 independent 6-MFMA chains
#pragma unroll
        for (int sub = 0; sub < 4; ++sub) {
            const int cl = sub * 16 + c;
            v8h Bfh0 = *(const v8h*)&B2h[cur][q][cl][0];
            v8h Bfh1 = *(const v8h*)&B2h[cur][4 + q][cl][0];
            v8h Bfl0 = *(const v8h*)&B2l[cur][q][cl][0];
            v8h Bfl1 = *(const v8h*)&B2l[cur][4 + q][cl][0];
            const unsigned kg = (unsigned)(kt * 64 + cl);
            const float cnc = cnorm[kg];    // 4 KB array, L1-hot
            v4f acc = {cnc, cnc, cnc, cnc}; // ||c||^2 preloaded; -2 folded in B
            acc = __builtin_amdgcn_mfma_f32_16x16x32_f16(Afh[0], Bfh0, acc, 0, 0, 0);
            acc = __builtin_amdgcn_mfma_f32_16x16x32_f16(Afh[1], Bfh1, acc, 0, 0, 0);
            acc = __builtin_amdgcn_mfma_f32_16x16x32_f16(Afh[0], Bfl0, acc, 0, 0, 0);
            acc = __builtin_amdgcn_mfma_f32_16x16x32_f16(Afh[1], Bfl1, acc, 0, 0, 0);
            acc = __builtin_amdgcn_mfma_f32_16x16x32_f16(Afl[0], Bfh0, acc, 0, 0, 0);
            acc = __builtin_amdgcn_mfma_f32_16x16x32_f16(Afl[1], Bfh1, acc, 0, 0, 0);
#pragma unroll
            for (int r = 0; r < 4; ++r) {
                // pack code index into low 10 mantissa bits (v_and_or_b32)
                unsigned vu = (__float_as_uint(acc[r]) & 0xFFFFFC00u) | kg;
                float vp = __uint_as_float(vu);
                // top-2 update: 2 ops (med3 + min)
                m2f[r] = __builtin_amdgcn_fmed3f(m1f[r], m2f[r], vp);
                m1f[r] = fminf(m1f[r], vp);
            }
        }

        __syncthreads();                    // single barrier per iteration
    }

    // ---- top-2 merge across the 16 lanes holding each row ----
#pragma unroll
    for (int r = 0; r < 4; ++r) {
        float a = m1f[r], b2 = m2f[r];
#pragma unroll
        for (int mask = 1; mask <= 8; mask <<= 1) {
            float o1 = __shfl_xor(a, mask, 64);
            float o2 = __shfl_xor(b2, mask, 64);
            float mx = fmaxf(a, o1);        // loser of champion duel
            a  = fminf(a, o1);
            b2 = fminf(fminf(b2, o2), mx);  // v_min3
        }
        if (c == 0) {
            int row = 16 * w + q * 4 + r;
            int i1 = (int)(__float_as_uint(a) & 1023u);
            idx_lds[row] = i1;
            // margin covers index-packing noise (<= |v|*4.9e-4) + fp16 hi/lo error
            float margin = fmaf(fabsf(a), 6e-4f, 0.0015f);
            if (b2 - a < margin) {
                int p = atomicAdd(&nflag, 1);
                flagrows[p] = row;
                flagi1[p] = i1;
                flagi2[p] = (int)(__float_as_uint(b2) & 1023u);
            }
        }
    }
    __syncthreads();

    // ---- exact fp32 top-2 recheck for flagged rows (one wave per row) ----
    {
        int nf = nflag;
        for (int f = w; f < nf; f += 8) {
            int row = flagrows[f], i1 = flagi1[f], i2x = flagi2[f];
            const float* zrow = zbase + row;
            float zj = zrow[(size_t)lane * HW];
            float p1 = zj * cbf[(size_t)i1  * DD + lane];
            float p2 = zj * cbf[(size_t)i2x * DD + lane];
#pragma unroll
            for (int mask = 1; mask <= 32; mask <<= 1) {
                p1 += __shfl_xor(p1, mask, 64);
                p2 += __shfl_xor(p2, mask, 64);
            }
            if (lane == 0) {
                float d1 = fmaf(-2.0f, p1, cnorm[i1]);
                float d2 = fmaf(-2.0f, p2, cnorm[i2x]);
                if (d2 < d1 || (d2 == d1 && i2x < i1)) idx_lds[row] = i2x;
            }
        }
    }
    __syncthreads();

    if (t < 128) {
        int bi = idx_lds[t];
        out[O_IDX + n0 + t] = (float)bi;
        idx16[n0 + t] = (unsigned short)bi;
    }
}

// Fused output pass: 256 blocks (j, chunk c). Reads z once: e_k_ste + segment sums
// + histogram (j==0) + L_commit partials. cb column j staged in LDS. idx as ushort.
__global__ __launch_bounds__(1024) void k_out(const unsigned short* __restrict__ idx16,
                                              const float* __restrict__ z_e,
                                              const float* __restrict__ cb,
                                              float* __restrict__ psum,
                                              int* __restrict__ pcnt,
                                              float* __restrict__ lc_part,
                                              float* __restrict__ out) {
    __shared__ float acc[KC];
    __shared__ int bins[KC];
    __shared__ float cbj[KC];
    __shared__ float lcr[16];
    const int j = blockIdx.x & 63;
    const int c = blockIdx.x >> 6;
    const int t = threadIdx.x;
    acc[t] = 0.f;
    bins[t] = 0;
    cbj[t] = cb[(size_t)t * DD + j];   // codebook column j (once per block)
    __syncthreads();
    const float* zj = z_e + (size_t)j * HW;
    float* oj = out + O_EK + (size_t)j * HW;
    const int base = c * 16384;
    float lc = 0.f;
#pragma unroll
    for (int i = 0; i < 4; ++i) {
        int n4 = base + i * 4096 + t * 4;
        int b = n4 >> 12, hw = n4 & 4095;
        size_t zoff = (size_t)b * (DD * HW) + hw;
        float4 z4 = *(const float4*)(zj + zoff);
        ushort4 k4 = *(const ushort4*)(idx16 + n4);
        float e0 = cbj[k4.x], e1 = cbj[k4.y], e2 = cbj[k4.z], e3 = cbj[k4.w];
        float4 o4 = { z4.x + (e0 - z4.x), z4.y + (e1 - z4.y),
                      z4.z + (e2 - z4.z), z4.w + (e3 - z4.w) };
        *(float4*)(oj + zoff) = o4;                       // coalesced
        float d0 = z4.x - e0, d1 = z4.y - e1, d2 = z4.z - e2, d3 = z4.w - e3;
        lc = fmaf(d0, d0, lc); lc = fmaf(d1, d1, lc);
        lc = fmaf(d2, d2, lc); lc = fmaf(d3, d3, lc);
        atomicAdd(&acc[k4.x], z4.x);
        atomicAdd(&acc[k4.y], z4.y);
        atomicAdd(&acc[k4.z], z4.z);
        atomicAdd(&acc[k4.w], z4.w);
        if (j == 0) {
            atomicAdd(&bins[k4.x], 1); atomicAdd(&bins[k4.y], 1);
            atomicAdd(&bins[k4.z], 1); atomicAdd(&bins[k4.w], 1);
        }
    }
    __syncthreads();
    psum[(size_t)c * 65536 + j * 1024 + t] = acc[t];
    if (j == 0) pcnt[c * 1024 + t] = bins[t];
#pragma unroll
    for (int m = 32; m >= 1; m >>= 1) lc += __shfl_xor(lc, m, 64);
    if ((t & 63) == 0) lcr[t >> 6] = lc;
    __syncthreads();
    if (t == 0) {
        float s = 0.f;
#pragma unroll
        for (int u = 0; u < 16; ++u) s += lcr[u];
        lc_part[blockIdx.x] = s;
    }
}

// Fused epilogue, coalesced on outputs: e = k*64+j. 64 blocks x 1024.
__global__ __launch_bounds__(1024) void k_epi(const float* __restrict__ psum,
                                              const int* __restrict__ pcnt,
                                              const float* __restrict__ ema_sum,
                                              const float* __restrict__ ema_count,
                                              const float* __restrict__ n_ws,
                                              const float* __restrict__ lc_part,
                                              float* __restrict__ out) {
    const int t = threadIdx.x;
    const int e = blockIdx.x * 1024 + t;
    const int k = e >> 6, j = e & 63;
    float s4 = psum[j * 1024 + k] + psum[65536 + j * 1024 + k]
             + psum[131072 + j * 1024 + k] + psum[196608 + j * 1024 + k];
    float ns = ema_sum[e] * 0.99f + 0.01f * s4;
    out[O_SUM + e] = ns;
    int cnt = pcnt[k] + pcnt[1024 + k] + pcnt[2048 + k] + pcnt[3072 + k];
    float nc = ema_count[k] * 0.99f + 0.01f * (float)cnt;
    float n  = n_ws[0];
    float cs = (nc + 1e-5f) / (n + 1024.0f * 1e-5f) * n;
    out[O_CB + e] = ns / cs;
    if (blockIdx.x == 0) {
        int c2 = pcnt[t] + pcnt[1024 + t] + pcnt[2048 + t] + pcnt[3072 + t];
        out[O_CNT + t] = ema_count[t] * 0.99f + 0.01f * (float)c2;
    }
    if (blockIdx.x == 1) {
        __shared__ float red[512];
        if (t < 512) red[t] = (t < 256) ? lc_part[t] : 0.f;
        __syncthreads();
        for (int s = 256; s >= 1; s >>= 1) {
            if (t < s) red[t] += red[t + s];
            __syncthreads();
        }
        if (t == 0) out[O_L] = 1.25f * red[0] * (1.0f / 4194304.0f);
    }
}

extern "C" void kernel_launch(void* const* d_in, const int* in_sizes, int n_in,
                              void* d_out, int out_size, void* d_ws, size_t ws_size,
                              hipStream_t stream) {
    const float* z_e       = (const float*)d_in[0];
    const float* cb        = (const float*)d_in[1];
    const float* ema_count = (const float*)d_in[2];
    const float* ema_sum   = (const float*)d_in[3];
    float* out             = (float*)d_out;

    float* ws_f      = (float*)d_ws;
    unsigned short* idx16 = (unsigned short*)d_ws;
    float* lc_part   = ws_f + WS_LCPART;
    float* n_ws      = ws_f + WS_N;
    float* cnorm_ws  = ws_f + WS_CNORM;
    float* psum      = ws_f + WS_PSUM;
    int*   pcnt      = (int*)(ws_f + WS_PCNT);
    unsigned short* cbh = (unsigned short*)(ws_f + WS_CBH);
    unsigned short* cbl = (unsigned short*)(ws_f + WS_CBL);

    k_pre<<<256, 256, 0, stream>>>(cb, ema_count, cnorm_ws, n_ws, cbh, cbl);
    k_argmin<<<NTOT / 128, 512, 0, stream>>>(z_e, cb, cbh, cbl, cnorm_ws, idx16, out);
    k_out<<<256, 1024, 0, stream>>>(idx16, z_e, cb, psum, pcnt, lc_part, out);
    k_epi<<<64, 1024, 0, stream>>>(psum, pcnt, ema_sum, ema_count, n_ws, lc_part, out);
}